// Round 9
// baseline (1525.920 us; speedup 1.0000x reference)
//
#include <hip/hip_runtime.h>
#include <hip/hip_bf16.h>
#include <hip/hip_fp16.h>

#define N_NODES 50000
#define MPAD    50048            // 391 * 128
#define NRB     391              // MPAD/128 row-blocks
#define N_EDGES 800000
#define IN_DIM  128
#define HID     256
#define QKVW    768              // q(256) | kv-interleaved(512)
#define N_LAYERS 8
#define OUT_DIM 40
#define SCALING 0.17677669529663687f

typedef __attribute__((ext_vector_type(8))) _Float16 f16x8;
typedef __attribute__((ext_vector_type(4))) float f32x4;

__device__ __forceinline__ void gload_lds16(const void* g, void* l) {
    __builtin_amdgcn_global_load_lds(
        (__attribute__((address_space(1))) const unsigned int*)g,
        (__attribute__((address_space(3))) unsigned int*)l, 16, 0, 0);
}

// ---------------- CSR build (by dst) ----------------
__global__ void hist_kernel(const int* __restrict__ dst, int* __restrict__ cnt, int E) {
    int e = blockIdx.x * blockDim.x + threadIdx.x;
    if (e < E) atomicAdd(&cnt[dst[e]], 1);
}

// single-block scan, wave-shfl based
__global__ __launch_bounds__(1024) void scan_kernel(const int* __restrict__ cnt,
                                                    int* __restrict__ row_off, int n) {
    __shared__ int wsum[16];
    __shared__ int carry_s;
    int tid = threadIdx.x;
    int lane = tid & 63, wid = tid >> 6;
    if (tid == 0) carry_s = 0;
    __syncthreads();
    for (int base = 0; base < n; base += 1024) {
        int i = base + tid;
        int x = (i < n) ? cnt[i] : 0;
        int v = x;
#pragma unroll
        for (int off = 1; off < 64; off <<= 1) {
            int y = __shfl_up(v, off);
            if (lane >= off) v += y;
        }
        if (lane == 63) wsum[wid] = v;
        __syncthreads();
        if (wid == 0) {
            int w = (lane < 16) ? wsum[lane] : 0;
#pragma unroll
            for (int off = 1; off < 16; off <<= 1) {
                int y = __shfl_up(w, off);
                if (lane >= off) w += y;
            }
            if (lane < 16) wsum[lane] = w;   // inclusive wave sums
        }
        __syncthreads();
        int wbase = (wid > 0) ? wsum[wid - 1] : 0;
        int carry = carry_s;
        if (i < n) row_off[i] = carry + wbase + v - x;   // exclusive
        int total = wsum[15];
        __syncthreads();
        if (tid == 0) carry_s = carry + total;
        __syncthreads();
    }
    if (tid == 0) row_off[n] = carry_s;
}

__global__ void scatter_kernel(const int* __restrict__ src, const int* __restrict__ dst,
                               const int* __restrict__ row_off, int* __restrict__ cur,
                               int* __restrict__ csr_src, int E) {
    int e = blockIdx.x * blockDim.x + threadIdx.x;
    if (e < E) {
        int d = dst[e];
        int pos = row_off[d] + atomicAdd(&cur[d], 1);
        csr_src[pos] = src[e];
    }
}

// Bucket-sort each dst's adjacency by src (1024-node buckets). Perf-only:
// aligns all waves' walk through src space so concurrent reads share the L2
// window. One wave per dst; ballot compaction for deg<=64, copy fallback else.
__global__ __launch_bounds__(256) void resort_kernel(
        const int* __restrict__ row_off, const int* __restrict__ csr_in,
        int* __restrict__ csr_out, int n) {
    int wave = threadIdx.x >> 6, lane = threadIdx.x & 63;
    int node = blockIdx.x * 4 + wave;
    if (node >= n) return;
    int beg = row_off[node], end = row_off[node + 1];
    int deg = end - beg;
    if (deg <= 64) {
        int sv = (lane < deg) ? csr_in[beg + lane] : 0;
        int b  = (lane < deg) ? (sv >> 10) : 63;   // real buckets 0..48
        int base = 0;
        for (int t = 0; t < 49; ++t) {
            unsigned long long mask = __ballot(b == t);
            if (b == t) {
                int pre = __popcll(mask & ((1ull << lane) - 1ull));
                csr_out[beg + base + pre] = sv;
            }
            base += __popcll(mask);
        }
    } else {
        for (int i = beg + lane; i < end; i += 64) csr_out[i] = csr_in[i];
    }
}

// ---------------- conversion kernels ----------------
__global__ void wqkv_cvt_kernel(const float* __restrict__ Wq, const float* __restrict__ Wk,
                                const float* __restrict__ Wv, _Float16* __restrict__ outw) {
    int i = blockIdx.x * blockDim.x + threadIdx.x;
    if (i >= N_LAYERS * QKVW * HID) return;
    int k = i & 255;
    int n = (i >> 8) % QKVW;
    int l = i / (QKVW * HID);
    int seg = n >> 8, nn = n & 255;
    const float* W = (seg == 0) ? Wq : (seg == 1) ? Wk : Wv;
    outw[i] = (_Float16)W[((size_t)l * HID + k) * HID + nn];
}

__global__ void win_cvt_kernel(const float* __restrict__ Win, _Float16* __restrict__ outw) {
    int i = blockIdx.x * blockDim.x + threadIdx.x;
    if (i >= HID * IN_DIM) return;
    int k = i & 127;
    int n = i >> 7;
    outw[i] = (_Float16)Win[(size_t)k * HID + n];
}

__global__ void wout_cvt_kernel(const float* __restrict__ Wout, _Float16* __restrict__ hi,
                                _Float16* __restrict__ lo) {
    int i = blockIdx.x * blockDim.x + threadIdx.x;
    if (i >= 128 * HID) return;
    int k = i & 255;
    int n = i >> 8;
    float v = (n < OUT_DIM) ? Wout[(size_t)k * OUT_DIM + n] : 0.f;
    _Float16 h = (_Float16)v;
    hi[i] = h;
    lo[i] = (_Float16)(v - (float)h);
}

__global__ void x_cvt_kernel(const float* __restrict__ X, _Float16* __restrict__ outx) {
    int i = blockIdx.x * blockDim.x + threadIdx.x;
    if (i >= MPAD * IN_DIM) return;
    int r = i >> 7;
    outx[i] = (_Float16)((r < N_NODES) ? X[i] : 0.f);
}

// ---------------- fp16 MFMA GEMM, dbuf + counted vmcnt + XCD-clustered tiles ----------
// C[MPAD, Nc] = (A @ B^T + bias)*scale ; A [MPAD][K] f16, B^T [Nc][K] f16, C f16.
// block 256 (4 waves), tile 128x128, BK=32, NT = K/32 tiles, NCOLT col-tiles.
// 1-D grid: b=(q*NCOLT+j)*8+x -> row=q*8+x, col=j; all col-tiles of a row share
// (b&7) => same XCD under round-robin dispatch => A-tile L2 reuse.
// KVILV: remap k/v output columns to interleaved layout (256+2d / 256+2d+1).
template<int NT, int NCOLT, bool KVILV>
__global__ __launch_bounds__(256) void gemm16(
        const _Float16* __restrict__ A, const _Float16* __restrict__ B,
        const float* __restrict__ bias0, const float* __restrict__ bias1,
        const float* __restrict__ bias2, float scale0,
        _Float16* __restrict__ C, int ldC) {
    __shared__ __align__(16) _Float16 lds[2][2 * 4096];   // [buf][A(8KB) | B(8KB)]
    const int K = NT * 32;

    const int bb = blockIdx.x;
    const int xx = bb & 7, tt = bb >> 3;
    const int qq = tt / NCOLT, jj = tt - qq * NCOLT;
    const int rowblk = qq * 8 + xx;
    if (rowblk >= NRB) return;
    const int row0 = rowblk * 128;
    const int n0   = jj * 128;

    const int tid  = threadIdx.x;
    const int lane = tid & 63;
    const int wave = tid >> 6;

    // staging: tile [128 rows][32 k] f16 = 512 16B-chunks, linear LDS.
    // chunk p holds k-chunk (p&3)^swz(row), swz(r) = (r&3)^((r>>2)&3) (involution)
    const int p0 = wave * 64 + lane;
    const int p1 = p0 + 256;
    auto srcoff = [&](int p, int grow0) -> size_t {
        int row = p >> 2, cir = p & 3;
        int sw  = (row & 3) ^ ((row >> 2) & 3);
        int sc  = cir ^ sw;
        return (size_t)(grow0 + row) * K + sc * 8;   // element offset
    };
    const size_t offA0 = srcoff(p0, row0), offA1 = srcoff(p1, row0);
    const size_t offB0 = srcoff(p0, n0),   offB1 = srcoff(p1, n0);
    const int d0 = wave * 512;
    const int d1 = 2048 + wave * 512;

    const int mh = (wave >> 1) * 64;
    const int nh = (wave & 1) * 64;
    int aoff[4], boff[4];
#pragma unroll
    for (int f = 0; f < 4; ++f) {
        int ra = mh + f * 16 + (lane & 15);
        int ca = (lane >> 4) ^ ((ra & 3) ^ ((ra >> 2) & 3));
        aoff[f] = ra * 64 + ca * 16;
        int rb = nh + f * 16 + (lane & 15);
        int cb = (lane >> 4) ^ ((rb & 3) ^ ((rb >> 2) & 3));
        boff[f] = rb * 64 + cb * 16;
    }

    f32x4 acc[4][4];
#pragma unroll
    for (int i = 0; i < 4; ++i)
#pragma unroll
        for (int j = 0; j < 4; ++j) acc[i][j] = {0.f, 0.f, 0.f, 0.f};

    auto STAGE = [&](int b, int t) {
        _Float16* LA = &lds[b][0];
        _Float16* LB = &lds[b][4096];
        const size_t k0 = (size_t)t * 32;
        gload_lds16(A + offA0 + k0, LA + d0);
        gload_lds16(A + offA1 + k0, LA + d1);
        gload_lds16(B + offB0 + k0, LB + d0);
        gload_lds16(B + offB1 + k0, LB + d1);
    };

    STAGE(0, 0);
#pragma unroll
    for (int t = 0; t < NT; ++t) {
        const int cur = t & 1;
        if (t + 1 < NT) {
            STAGE(cur ^ 1, t + 1);
            asm volatile("s_waitcnt vmcnt(4)" ::: "memory");   // drain only buf[cur]'s loads
        } else {
            asm volatile("s_waitcnt vmcnt(0)" ::: "memory");
        }
        __builtin_amdgcn_s_barrier();
        const char* baseA = (const char*)&lds[cur][0];
        const char* baseB = (const char*)&lds[cur][4096];
        f16x8 af[4];
#pragma unroll
        for (int i = 0; i < 4; ++i)
            af[i] = *reinterpret_cast<const f16x8*>(baseA + aoff[i]);
#pragma unroll
        for (int j = 0; j < 4; ++j) {
            f16x8 bf = *reinterpret_cast<const f16x8*>(baseB + boff[j]);
#pragma unroll
            for (int i = 0; i < 4; ++i)
                acc[i][j] = __builtin_amdgcn_mfma_f32_16x16x32_f16(af[i], bf, acc[i][j], 0, 0, 0);
        }
        __builtin_amdgcn_s_barrier();   // buf[cur] free for overwrite next iter
    }

    const int seg = n0 >> 8;
    const float* bias = (seg == 0) ? bias0 : (seg == 1) ? bias1 : bias2;
    const float scale = (seg == 0) ? scale0 : 1.f;
    const int fq = lane >> 4;
    const int fr = lane & 15;
#pragma unroll
    for (int i = 0; i < 4; ++i) {
#pragma unroll
        for (int j = 0; j < 4; ++j) {
#pragma unroll
            for (int r = 0; r < 4; ++r) {
                int m = row0 + mh + i * 16 + fq * 4 + r;
                int n = n0 + nh + j * 16 + fr;
                float o = (acc[i][j][r] + bias[n & 255]) * scale;
                int col = n;
                if (KVILV && n >= 256) col = 256 + 2 * (n & 255) + (n >= 512 ? 1 : 0);
                C[(size_t)m * ldC + col] = (_Float16)o;
            }
        }
    }
}

// ---------------- out_proj: 2-term fp16 W split, fp32 out, guarded ----------------
__global__ __launch_bounds__(256) void gemm_out(
        const _Float16* __restrict__ A, const _Float16* __restrict__ Bh,
        const _Float16* __restrict__ Bl, const float* __restrict__ bias,
        float* __restrict__ C, int K) {
    __shared__ __align__(16) _Float16 lds[2][3 * 4096];

    const int tid  = threadIdx.x;
    const int lane = tid & 63;
    const int wave = tid >> 6;
    const int row0 = blockIdx.x * 128;

    const int p0 = wave * 64 + lane;
    const int p1 = p0 + 256;
    auto srcoff = [&](int p, int grow0) -> size_t {
        int row = p >> 2, cir = p & 3;
        int sw  = (row & 3) ^ ((row >> 2) & 3);
        int sc  = cir ^ sw;
        return (size_t)(grow0 + row) * K + sc * 8;
    };
    const size_t offA0 = srcoff(p0, row0), offA1 = srcoff(p1, row0);
    const size_t offB0 = srcoff(p0, 0),    offB1 = srcoff(p1, 0);
    const int d0 = wave * 512;
    const int d1 = 2048 + wave * 512;

    const int mh = (wave >> 1) * 64;
    const int nh = (wave & 1) * 64;
    int aoff[4], boff[4];
#pragma unroll
    for (int f = 0; f < 4; ++f) {
        int ra = mh + f * 16 + (lane & 15);
        int ca = (lane >> 4) ^ ((ra & 3) ^ ((ra >> 2) & 3));
        aoff[f] = ra * 64 + ca * 16;
        int rb = nh + f * 16 + (lane & 15);
        int cb = (lane >> 4) ^ ((rb & 3) ^ ((rb >> 2) & 3));
        boff[f] = rb * 64 + cb * 16;
    }

    f32x4 acc[4][4];
#pragma unroll
    for (int i = 0; i < 4; ++i)
#pragma unroll
        for (int j = 0; j < 4; ++j) acc[i][j] = {0.f, 0.f, 0.f, 0.f};

    auto STAGE = [&](int b, int t) {
        _Float16* LA  = &lds[b][0];
        _Float16* LBh = &lds[b][4096];
        _Float16* LBl = &lds[b][8192];
        const size_t k0 = (size_t)t * 32;
        gload_lds16(A  + offA0 + k0, LA  + d0);
        gload_lds16(A  + offA1 + k0, LA  + d1);
        gload_lds16(Bh + offB0 + k0, LBh + d0);
        gload_lds16(Bh + offB1 + k0, LBh + d1);
        gload_lds16(Bl + offB0 + k0, LBl + d0);
        gload_lds16(Bl + offB1 + k0, LBl + d1);
    };

    STAGE(0, 0);
#pragma unroll
    for (int t = 0; t < 8; ++t) {
        const int cur = t & 1;
        if (t + 1 < 8) {
            STAGE(cur ^ 1, t + 1);
            asm volatile("s_waitcnt vmcnt(6)" ::: "memory");
        } else {
            asm volatile("s_waitcnt vmcnt(0)" ::: "memory");
        }
        __builtin_amdgcn_s_barrier();
        const char* baseA  = (const char*)&lds[cur][0];
        const char* baseBh = (const char*)&lds[cur][4096];
        const char* baseBl = (const char*)&lds[cur][8192];
        f16x8 af[4];
#pragma unroll
        for (int i = 0; i < 4; ++i)
            af[i] = *reinterpret_cast<const f16x8*>(baseA + aoff[i]);
#pragma unroll
        for (int j = 0; j < 4; ++j) {
            f16x8 bh = *reinterpret_cast<const f16x8*>(baseBh + boff[j]);
            f16x8 bl = *reinterpret_cast<const f16x8*>(baseBl + boff[j]);
#pragma unroll
            for (int i = 0; i < 4; ++i) {
                acc[i][j] = __builtin_amdgcn_mfma_f32_16x16x32_f16(af[i], bh, acc[i][j], 0, 0, 0);
                acc[i][j] = __builtin_amdgcn_mfma_f32_16x16x32_f16(af[i], bl, acc[i][j], 0, 0, 0);
            }
        }
        __builtin_amdgcn_s_barrier();
    }

    const int fq = lane >> 4;
    const int fr = lane & 15;
#pragma unroll
    for (int i = 0; i < 4; ++i) {
#pragma unroll
        for (int j = 0; j < 4; ++j) {
#pragma unroll
            for (int r = 0; r < 4; ++r) {
                int m = row0 + mh + i * 16 + fq * 4 + r;
                int n = nh + j * 16 + fr;
                if (m < N_NODES && n < OUT_DIM)
                    C[(size_t)m * OUT_DIM + n] = acc[i][j][r] + bias[n];
            }
        }
    }
}

// ---------------- fused SDDMM + segment-softmax + SpMM ----------------
// one wave per dst node; lane -> head = lane>>3, dims lane*4 .. +4; 4-edge unroll.
// qkv rows: [q(256) | kv-interleaved(512)]: k_d at 256+2d, v_d at 256+2d+1.
// Each edge = one float4 load (16B: k0 v0 k1 v1 k2 v2 k3 v3 for this lane's dims).
struct KVf { float2 p0, p1, p2, p3; };
__device__ __forceinline__ KVf unpack_kv(const float4& r) {
    const __half2* h = reinterpret_cast<const __half2*>(&r);
    KVf o;
    o.p0 = __half22float2(h[0]); o.p1 = __half22float2(h[1]);
    o.p2 = __half22float2(h[2]); o.p3 = __half22float2(h[3]);
    return o;
}
__device__ __forceinline__ float dot_kv(const float4& q, const KVf& kv) {
    float d = q.x * kv.p0.x + q.y * kv.p1.x + q.z * kv.p2.x + q.w * kv.p3.x;
    d += __shfl_xor(d, 1);
    d += __shfl_xor(d, 2);
    d += __shfl_xor(d, 4);
    return d;
}
__device__ __forceinline__ void vadd_kv(float4& acc, float p, const KVf& kv) {
    acc.x = fmaf(p, kv.p0.y, acc.x);
    acc.y = fmaf(p, kv.p1.y, acc.y);
    acc.z = fmaf(p, kv.p2.y, acc.z);
    acc.w = fmaf(p, kv.p3.y, acc.w);
}

__global__ __launch_bounds__(256) void attn_kernel(
        const _Float16* __restrict__ qkv, const int* __restrict__ row_off,
        const int* __restrict__ csr_src, _Float16* __restrict__ h_out, int n) {
    int wave = threadIdx.x >> 6;
    int lane = threadIdx.x & 63;
    int node = blockIdx.x * 4 + wave;
    if (node >= n) return;
    const int loff = lane * 4;
    float4 qv;
    {
        float2 raw = *reinterpret_cast<const float2*>(&qkv[(size_t)node * QKVW + loff]);
        const __half2* h2 = reinterpret_cast<const __half2*>(&raw);
        float2 a = __half22float2(h2[0]), b = __half22float2(h2[1]);
        qv = make_float4(a.x, a.y, b.x, b.y);
    }
    float4 acc = make_float4(0.f, 0.f, 0.f, 0.f);
    float m = -INFINITY, s = 0.f;
    int beg = row_off[node], end = row_off[node + 1];
    int idx = beg;
    const int koff = HID + 2 * loff;

    for (; idx + 3 < end; idx += 4) {
        int s0 = csr_src[idx], s1 = csr_src[idx + 1];
        int s2 = csr_src[idx + 2], s3 = csr_src[idx + 3];
        float4 r0 = *(const float4*)(qkv + (size_t)s0 * QKVW + koff);
        float4 r1 = *(const float4*)(qkv + (size_t)s1 * QKVW + koff);
        float4 r2 = *(const float4*)(qkv + (size_t)s2 * QKVW + koff);
        float4 r3 = *(const float4*)(qkv + (size_t)s3 * QKVW + koff);
        KVf kv0 = unpack_kv(r0), kv1 = unpack_kv(r1);
        KVf kv2 = unpack_kv(r2), kv3 = unpack_kv(r3);
        float e0 = dot_kv(qv, kv0), e1 = dot_kv(qv, kv1);
        float e2 = dot_kv(qv, kv2), e3 = dot_kv(qv, kv3);
        float mn = fmaxf(fmaxf(fmaxf(m, e0), fmaxf(e1, e2)), e3);
        float c  = __expf(m - mn);
        float p0 = __expf(e0 - mn), p1 = __expf(e1 - mn);
        float p2 = __expf(e2 - mn), p3 = __expf(e3 - mn);
        s = fmaf(s, c, (p0 + p1) + (p2 + p3));
        acc.x *= c; acc.y *= c; acc.z *= c; acc.w *= c;
        vadd_kv(acc, p0, kv0); vadd_kv(acc, p1, kv1);
        vadd_kv(acc, p2, kv2); vadd_kv(acc, p3, kv3);
        m = mn;
    }
    for (; idx < end; ++idx) {
        int s0 = csr_src[idx];
        float4 r0 = *(const float4*)(qkv + (size_t)s0 * QKVW + koff);
        KVf kv0 = unpack_kv(r0);
        float e0 = dot_kv(qv, kv0);
        float mn = fmaxf(m, e0);
        float c = __expf(m - mn);
        float p0 = __expf(e0 - mn);
        s = fmaf(s, c, p0);
        acc.x *= c; acc.y *= c; acc.z *= c; acc.w *= c;
        vadd_kv(acc, p0, kv0);
        m = mn;
    }

    float inv = (s > 0.f) ? 1.f / s : 0.f;
    __half2 o01 = __floats2half2_rn(acc.x * inv, acc.y * inv);
    __half2 o23 = __floats2half2_rn(acc.z * inv, acc.w * inv);
    union { __half2 h2[2]; float2 f2; } u;
    u.h2[0] = o01; u.h2[1] = o23;
    *reinterpret_cast<float2*>(&h_out[(size_t)node * HID + loff]) = u.f2;
}

extern "C" void kernel_launch(void* const* d_in, const int* in_sizes, int n_in,
                              void* d_out, int out_size, void* d_ws, size_t ws_size,
                              hipStream_t stream) {
    const float* X    = (const float*)d_in[0];
    const int*   src  = (const int*)d_in[1];
    const int*   dst  = (const int*)d_in[2];
    const float* Win  = (const float*)d_in[3];
    const float* bin_ = (const float*)d_in[4];
    const float* Wq   = (const float*)d_in[5];
    const float* Wk   = (const float*)d_in[6];
    const float* Wv   = (const float*)d_in[7];
    const float* bq   = (const float*)d_in[8];
    const float* bk   = (const float*)d_in[9];
    const float* bv   = (const float*)d_in[10];
    const float* Wout = (const float*)d_in[11];
    const float* bout = (const float*)d_in[12];
    float* out = (float*)d_out;

    char* ws = (char*)d_ws;
    size_t off = 0;
    auto alloc = [&](size_t bytes) -> void* {
        void* p = ws + off;
        off = (off + bytes + 255) & ~(size_t)255;
        return p;
    };
    _Float16* qkv   = (_Float16*)alloc((size_t)MPAD * QKVW * 2);
    _Float16* h     = (_Float16*)alloc((size_t)MPAD * HID * 2);
    _Float16* Xf    = (_Float16*)alloc((size_t)MPAD * IN_DIM * 2);
    _Float16* Wqkvt = (_Float16*)alloc((size_t)N_LAYERS * QKVW * HID * 2);
    _Float16* Wint  = (_Float16*)alloc((size_t)HID * IN_DIM * 2);
    _Float16* Wot_h = (_Float16*)alloc((size_t)128 * HID * 2);
    _Float16* Wot_l = (_Float16*)alloc((size_t)128 * HID * 2);
    int* cnt     = (int*)alloc(sizeof(int) * N_NODES);
    int* row_off = (int*)alloc(sizeof(int) * (N_NODES + 1));
    int* csr_tmp = (int*)alloc(sizeof(int) * N_EDGES);
    int* csr_srt = (int*)alloc(sizeof(int) * N_EDGES);

    // CSR build (+ per-dst src-bucket sort for L2 window alignment)
    hipMemsetAsync(cnt, 0, sizeof(int) * N_NODES, stream);
    hist_kernel<<<(N_EDGES + 255) / 256, 256, 0, stream>>>(dst, cnt, N_EDGES);
    scan_kernel<<<1, 1024, 0, stream>>>(cnt, row_off, N_NODES);
    hipMemsetAsync(cnt, 0, sizeof(int) * N_NODES, stream);
    scatter_kernel<<<(N_EDGES + 255) / 256, 256, 0, stream>>>(src, dst, row_off, cnt, csr_tmp, N_EDGES);
    resort_kernel<<<(N_NODES + 3) / 4, 256, 0, stream>>>(row_off, csr_tmp, csr_srt, N_NODES);

    // conversions
    {
        int t1 = N_LAYERS * QKVW * HID;
        wqkv_cvt_kernel<<<(t1 + 255) / 256, 256, 0, stream>>>(Wq, Wk, Wv, Wqkvt);
        int t2 = HID * IN_DIM;
        win_cvt_kernel<<<(t2 + 255) / 256, 256, 0, stream>>>(Win, Wint);
        int t3 = 128 * HID;
        wout_cvt_kernel<<<(t3 + 255) / 256, 256, 0, stream>>>(Wout, Wot_h, Wot_l);
        int t4 = MPAD * IN_DIM;
        x_cvt_kernel<<<(t4 + 255) / 256, 256, 0, stream>>>(X, Xf);
    }

    dim3 blk(256);
    const int NQ = 8 * ((NRB + 7) / 8);   // 392 row-slots
    // in_proj: h = X @ Win + bin  (fp16 out, ldC=256), K=128 -> NT=4, 2 col-tiles
    gemm16<4, 2, false><<<dim3(NQ * 2), blk, 0, stream>>>(
        Xf, Wint, bin_, bin_, bin_, 1.f, h, HID);

    for (int l = 0; l < N_LAYERS; ++l) {
        const _Float16* Bl = Wqkvt + (size_t)l * QKVW * HID;
        // fused QKV (kv interleaved out): K=256 -> NT=8, 6 col-tiles
        gemm16<8, 6, true><<<dim3(NQ * 6), blk, 0, stream>>>(
            h, Bl, bq + l * HID, bk + l * HID, bv + l * HID, SCALING, qkv, QKVW);
        attn_kernel<<<(N_NODES + 3) / 4, blk, 0, stream>>>(
            qkv, row_off, csr_srt, h, N_NODES);
    }
    // out_proj
    gemm_out<<<dim3(NRB), blk, 0, stream>>>(
        h, Wot_h, Wot_l, bout, out, HID);
}

// Round 10
// 1422.485 us; speedup vs baseline: 1.0727x; 1.0727x over previous
//
#include <hip/hip_runtime.h>
#include <hip/hip_bf16.h>
#include <hip/hip_fp16.h>

#define N_NODES 50000
#define MPAD    50048            // 391 * 128
#define NRB     391              // MPAD/128 row-blocks
#define N_EDGES 800000
#define IN_DIM  128
#define HID     256
#define QKVW    768              // q | k | v concatenated row
#define N_LAYERS 8
#define OUT_DIM 40
#define SCALING 0.17677669529663687f

typedef __attribute__((ext_vector_type(8))) _Float16 f16x8;
typedef __attribute__((ext_vector_type(4))) float f32x4;

__device__ __forceinline__ void gload_lds16(const void* g, void* l) {
    __builtin_amdgcn_global_load_lds(
        (__attribute__((address_space(1))) const unsigned int*)g,
        (__attribute__((address_space(3))) unsigned int*)l, 16, 0, 0);
}

// ---------------- CSR build (by dst) ----------------
__global__ void hist_kernel(const int* __restrict__ dst, int* __restrict__ cnt, int E) {
    int e = blockIdx.x * blockDim.x + threadIdx.x;
    if (e < E) atomicAdd(&cnt[dst[e]], 1);
}

// single-block scan, wave-shfl based
__global__ __launch_bounds__(1024) void scan_kernel(const int* __restrict__ cnt,
                                                    int* __restrict__ row_off, int n) {
    __shared__ int wsum[16];
    __shared__ int carry_s;
    int tid = threadIdx.x;
    int lane = tid & 63, wid = tid >> 6;
    if (tid == 0) carry_s = 0;
    __syncthreads();
    for (int base = 0; base < n; base += 1024) {
        int i = base + tid;
        int x = (i < n) ? cnt[i] : 0;
        int v = x;
#pragma unroll
        for (int off = 1; off < 64; off <<= 1) {
            int y = __shfl_up(v, off);
            if (lane >= off) v += y;
        }
        if (lane == 63) wsum[wid] = v;
        __syncthreads();
        if (wid == 0) {
            int w = (lane < 16) ? wsum[lane] : 0;
#pragma unroll
            for (int off = 1; off < 16; off <<= 1) {
                int y = __shfl_up(w, off);
                if (lane >= off) w += y;
            }
            if (lane < 16) wsum[lane] = w;   // inclusive wave sums
        }
        __syncthreads();
        int wbase = (wid > 0) ? wsum[wid - 1] : 0;
        int carry = carry_s;
        if (i < n) row_off[i] = carry + wbase + v - x;   // exclusive
        int total = wsum[15];
        __syncthreads();
        if (tid == 0) carry_s = carry + total;
        __syncthreads();
    }
    if (tid == 0) row_off[n] = carry_s;
}

__global__ void scatter_kernel(const int* __restrict__ src, const int* __restrict__ dst,
                               const int* __restrict__ row_off, int* __restrict__ cur,
                               int* __restrict__ csr_src, int E) {
    int e = blockIdx.x * blockDim.x + threadIdx.x;
    if (e < E) {
        int d = dst[e];
        int pos = row_off[d] + atomicAdd(&cur[d], 1);
        csr_src[pos] = src[e];
    }
}

// ---------------- conversion kernels ----------------
__global__ void wqkv_cvt_kernel(const float* __restrict__ Wq, const float* __restrict__ Wk,
                                const float* __restrict__ Wv, _Float16* __restrict__ outw) {
    int i = blockIdx.x * blockDim.x + threadIdx.x;
    if (i >= N_LAYERS * QKVW * HID) return;
    int k = i & 255;
    int n = (i >> 8) % QKVW;
    int l = i / (QKVW * HID);
    int seg = n >> 8, nn = n & 255;
    const float* W = (seg == 0) ? Wq : (seg == 1) ? Wk : Wv;
    outw[i] = (_Float16)W[((size_t)l * HID + k) * HID + nn];
}

__global__ void win_cvt_kernel(const float* __restrict__ Win, _Float16* __restrict__ outw) {
    int i = blockIdx.x * blockDim.x + threadIdx.x;
    if (i >= HID * IN_DIM) return;
    int k = i & 127;
    int n = i >> 7;
    outw[i] = (_Float16)Win[(size_t)k * HID + n];
}

__global__ void wout_cvt_kernel(const float* __restrict__ Wout, _Float16* __restrict__ hi,
                                _Float16* __restrict__ lo) {
    int i = blockIdx.x * blockDim.x + threadIdx.x;
    if (i >= 128 * HID) return;
    int k = i & 255;
    int n = i >> 8;
    float v = (n < OUT_DIM) ? Wout[(size_t)k * OUT_DIM + n] : 0.f;
    _Float16 h = (_Float16)v;
    hi[i] = h;
    lo[i] = (_Float16)(v - (float)h);
}

__global__ void x_cvt_kernel(const float* __restrict__ X, _Float16* __restrict__ outx) {
    int i = blockIdx.x * blockDim.x + threadIdx.x;
    if (i >= MPAD * IN_DIM) return;
    int r = i >> 7;
    outx[i] = (_Float16)((r < N_NODES) ? X[i] : 0.f);
}

// ---------------- fp16 MFMA GEMM: 3-buffer LDS, 2-tiles-ahead prefetch ----------------
// C[MPAD, Nc] = (A @ B^T + bias)*scale ; A [MPAD][K] f16, B^T [Nc][K] f16, C f16.
// block 256 (4 waves), tile 128x128, BK=32, NT = K/32 tiles, NCOLT col-tiles.
// 1-D grid: b=(q*NCOLT+j)*8+x -> row=q*8+x, col=j; all col-tiles of a row share
// (b&7) => same XCD under round-robin dispatch => A-tile L2 reuse (round-7 win).
// Pipeline: stage t+2, wait vmcnt(8) (tiles t+1,t+2 stay in flight) -> 2-deep.
template<int NT, int NCOLT>
__global__ __launch_bounds__(256) void gemm16(
        const _Float16* __restrict__ A, const _Float16* __restrict__ B,
        const float* __restrict__ bias0, const float* __restrict__ bias1,
        const float* __restrict__ bias2, float scale0,
        _Float16* __restrict__ C, int ldC) {
    __shared__ __align__(16) _Float16 lds[3][2 * 4096];   // 3 x [A(8KB)|B(8KB)] = 48KB
    const int K = NT * 32;

    const int bb = blockIdx.x;
    const int xx = bb & 7, tt = bb >> 3;
    const int qq = tt / NCOLT, jj = tt - qq * NCOLT;
    const int rowblk = qq * 8 + xx;
    if (rowblk >= NRB) return;
    const int row0 = rowblk * 128;
    const int n0   = jj * 128;

    const int tid  = threadIdx.x;
    const int lane = tid & 63;
    const int wave = tid >> 6;

    // staging: tile [128 rows][32 k] f16 = 512 16B-chunks, linear LDS.
    // chunk p holds k-chunk (p&3)^swz(row), swz(r) = (r&3)^((r>>2)&3) (involution)
    const int p0 = wave * 64 + lane;
    const int p1 = p0 + 256;
    auto srcoff = [&](int p, int grow0) -> size_t {
        int row = p >> 2, cir = p & 3;
        int sw  = (row & 3) ^ ((row >> 2) & 3);
        int sc  = cir ^ sw;
        return (size_t)(grow0 + row) * K + sc * 8;   // element offset
    };
    const size_t offA0 = srcoff(p0, row0), offA1 = srcoff(p1, row0);
    const size_t offB0 = srcoff(p0, n0),   offB1 = srcoff(p1, n0);
    const int d0 = wave * 512;
    const int d1 = 2048 + wave * 512;

    const int mh = (wave >> 1) * 64;
    const int nh = (wave & 1) * 64;
    int aoff[4], boff[4];
#pragma unroll
    for (int f = 0; f < 4; ++f) {
        int ra = mh + f * 16 + (lane & 15);
        int ca = (lane >> 4) ^ ((ra & 3) ^ ((ra >> 2) & 3));
        aoff[f] = ra * 64 + ca * 16;
        int rb = nh + f * 16 + (lane & 15);
        int cb = (lane >> 4) ^ ((rb & 3) ^ ((rb >> 2) & 3));
        boff[f] = rb * 64 + cb * 16;
    }

    f32x4 acc[4][4];
#pragma unroll
    for (int i = 0; i < 4; ++i)
#pragma unroll
        for (int j = 0; j < 4; ++j) acc[i][j] = {0.f, 0.f, 0.f, 0.f};

    auto STAGE = [&](int b, int t) {
        _Float16* LA = &lds[b][0];
        _Float16* LB = &lds[b][4096];
        const size_t k0 = (size_t)t * 32;
        gload_lds16(A + offA0 + k0, LA + d0);
        gload_lds16(A + offA1 + k0, LA + d1);
        gload_lds16(B + offB0 + k0, LB + d0);
        gload_lds16(B + offB1 + k0, LB + d1);
    };

    STAGE(0, 0);
    STAGE(1, 1);   // NT >= 2 always here
#pragma unroll
    for (int t = 0; t < NT; ++t) {
        if (t + 2 < NT) {
            STAGE((t + 2) % 3, t + 2);
            asm volatile("s_waitcnt vmcnt(8)" ::: "memory");   // tile t done; t+1,t+2 in flight
        } else if (t + 1 < NT) {
            asm volatile("s_waitcnt vmcnt(4)" ::: "memory");   // tile t done; t+1 in flight
        } else {
            asm volatile("s_waitcnt vmcnt(0)" ::: "memory");
        }
        __builtin_amdgcn_s_barrier();
        const char* baseA = (const char*)&lds[t % 3][0];
        const char* baseB = (const char*)&lds[t % 3][4096];
        f16x8 af[4];
#pragma unroll
        for (int i = 0; i < 4; ++i)
            af[i] = *reinterpret_cast<const f16x8*>(baseA + aoff[i]);
#pragma unroll
        for (int j = 0; j < 4; ++j) {
            f16x8 bf = *reinterpret_cast<const f16x8*>(baseB + boff[j]);
#pragma unroll
            for (int i = 0; i < 4; ++i)
                acc[i][j] = __builtin_amdgcn_mfma_f32_16x16x32_f16(af[i], bf, acc[i][j], 0, 0, 0);
        }
        __builtin_amdgcn_s_barrier();   // buf (t%3) free for overwrite at t+3
    }

    const int seg = n0 >> 8;
    const float* bias = (seg == 0) ? bias0 : (seg == 1) ? bias1 : bias2;
    const float scale = (seg == 0) ? scale0 : 1.f;
    const int fq = lane >> 4;
    const int fr = lane & 15;
#pragma unroll
    for (int i = 0; i < 4; ++i) {
#pragma unroll
        for (int j = 0; j < 4; ++j) {
#pragma unroll
            for (int r = 0; r < 4; ++r) {
                int m = row0 + mh + i * 16 + fq * 4 + r;
                int n = n0 + nh + j * 16 + fr;
                float o = (acc[i][j][r] + bias[n & 255]) * scale;
                C[(size_t)m * ldC + n] = (_Float16)o;
            }
        }
    }
}

// ---------------- out_proj: 2-term fp16 W split, fp32 out, guarded; 3-buffer ----------
__global__ __launch_bounds__(256) void gemm_out(
        const _Float16* __restrict__ A, const _Float16* __restrict__ Bh,
        const _Float16* __restrict__ Bl, const float* __restrict__ bias,
        float* __restrict__ C, int K) {
    __shared__ __align__(16) _Float16 lds[3][3 * 4096];   // 72KB

    const int tid  = threadIdx.x;
    const int lane = tid & 63;
    const int wave = tid >> 6;
    const int row0 = blockIdx.x * 128;

    const int p0 = wave * 64 + lane;
    const int p1 = p0 + 256;
    auto srcoff = [&](int p, int grow0) -> size_t {
        int row = p >> 2, cir = p & 3;
        int sw  = (row & 3) ^ ((row >> 2) & 3);
        int sc  = cir ^ sw;
        return (size_t)(grow0 + row) * K + sc * 8;
    };
    const size_t offA0 = srcoff(p0, row0), offA1 = srcoff(p1, row0);
    const size_t offB0 = srcoff(p0, 0),    offB1 = srcoff(p1, 0);
    const int d0 = wave * 512;
    const int d1 = 2048 + wave * 512;

    const int mh = (wave >> 1) * 64;
    const int nh = (wave & 1) * 64;
    int aoff[4], boff[4];
#pragma unroll
    for (int f = 0; f < 4; ++f) {
        int ra = mh + f * 16 + (lane & 15);
        int ca = (lane >> 4) ^ ((ra & 3) ^ ((ra >> 2) & 3));
        aoff[f] = ra * 64 + ca * 16;
        int rb = nh + f * 16 + (lane & 15);
        int cb = (lane >> 4) ^ ((rb & 3) ^ ((rb >> 2) & 3));
        boff[f] = rb * 64 + cb * 16;
    }

    f32x4 acc[4][4];
#pragma unroll
    for (int i = 0; i < 4; ++i)
#pragma unroll
        for (int j = 0; j < 4; ++j) acc[i][j] = {0.f, 0.f, 0.f, 0.f};

    auto STAGE = [&](int b, int t) {
        _Float16* LA  = &lds[b][0];
        _Float16* LBh = &lds[b][4096];
        _Float16* LBl = &lds[b][8192];
        const size_t k0 = (size_t)t * 32;
        gload_lds16(A  + offA0 + k0, LA  + d0);
        gload_lds16(A  + offA1 + k0, LA  + d1);
        gload_lds16(Bh + offB0 + k0, LBh + d0);
        gload_lds16(Bh + offB1 + k0, LBh + d1);
        gload_lds16(Bl + offB0 + k0, LBl + d0);
        gload_lds16(Bl + offB1 + k0, LBl + d1);
    };

    STAGE(0, 0);
    STAGE(1, 1);
#pragma unroll
    for (int t = 0; t < 8; ++t) {
        if (t + 2 < 8) {
            STAGE((t + 2) % 3, t + 2);
            asm volatile("s_waitcnt vmcnt(12)" ::: "memory");
        } else if (t + 1 < 8) {
            asm volatile("s_waitcnt vmcnt(6)" ::: "memory");
        } else {
            asm volatile("s_waitcnt vmcnt(0)" ::: "memory");
        }
        __builtin_amdgcn_s_barrier();
        const char* baseA  = (const char*)&lds[t % 3][0];
        const char* baseBh = (const char*)&lds[t % 3][4096];
        const char* baseBl = (const char*)&lds[t % 3][8192];
        f16x8 af[4];
#pragma unroll
        for (int i = 0; i < 4; ++i)
            af[i] = *reinterpret_cast<const f16x8*>(baseA + aoff[i]);
#pragma unroll
        for (int j = 0; j < 4; ++j) {
            f16x8 bh = *reinterpret_cast<const f16x8*>(baseBh + boff[j]);
            f16x8 bl = *reinterpret_cast<const f16x8*>(baseBl + boff[j]);
#pragma unroll
            for (int i = 0; i < 4; ++i) {
                acc[i][j] = __builtin_amdgcn_mfma_f32_16x16x32_f16(af[i], bh, acc[i][j], 0, 0, 0);
                acc[i][j] = __builtin_amdgcn_mfma_f32_16x16x32_f16(af[i], bl, acc[i][j], 0, 0, 0);
            }
        }
        __builtin_amdgcn_s_barrier();
    }

    const int fq = lane >> 4;
    const int fr = lane & 15;
#pragma unroll
    for (int i = 0; i < 4; ++i) {
#pragma unroll
        for (int j = 0; j < 4; ++j) {
#pragma unroll
            for (int r = 0; r < 4; ++r) {
                int m = row0 + mh + i * 16 + fq * 4 + r;
                int n = nh + j * 16 + fr;
                if (m < N_NODES && n < OUT_DIM)
                    C[(size_t)m * OUT_DIM + n] = acc[i][j][r] + bias[n];
            }
        }
    }
}

// ---------------- fused SDDMM + segment-softmax + SpMM (round-6 form, best) ----------
// one wave per dst node; lane -> head = lane>>3, dims lane*4 .. +4; 4-edge unroll.
// qkv rows: [q(256) | k(256) | v(256)] fp16
__global__ __launch_bounds__(256) void attn_kernel(
        const _Float16* __restrict__ qkv, const int* __restrict__ row_off,
        const int* __restrict__ csr_src, _Float16* __restrict__ h_out, int n) {
    int wave = threadIdx.x >> 6;
    int lane = threadIdx.x & 63;
    int node = blockIdx.x * 4 + wave;
    if (node >= n) return;
    const int loff = lane * 4;
    float4 qv;
    {
        float2 raw = *reinterpret_cast<const float2*>(&qkv[(size_t)node * QKVW + loff]);
        const __half2* h2 = reinterpret_cast<const __half2*>(&raw);
        float2 a = __half22float2(h2[0]), b = __half22float2(h2[1]);
        qv = make_float4(a.x, a.y, b.x, b.y);
    }
    float4 acc = make_float4(0.f, 0.f, 0.f, 0.f);
    float m = -INFINITY, s = 0.f;
    int beg = row_off[node], end = row_off[node + 1];
    int idx = beg;

#define LOAD_KV(slot, sn)                                                                 \
    float2 kr##slot, vr##slot;                                                            \
    {                                                                                     \
        const _Float16* base = qkv + (size_t)(sn) * QKVW;                                 \
        kr##slot = *reinterpret_cast<const float2*>(base + HID + loff);                   \
        vr##slot = *reinterpret_cast<const float2*>(base + 2 * HID + loff);               \
    }

#define DOT(slot, dvar)                                                                   \
    float dvar;                                                                           \
    {                                                                                     \
        const __half2* kh = reinterpret_cast<const __half2*>(&kr##slot);                  \
        float2 k01 = __half22float2(kh[0]), k23 = __half22float2(kh[1]);                  \
        dvar = qv.x * k01.x + qv.y * k01.y + qv.z * k23.x + qv.w * k23.y;                 \
        dvar += __shfl_xor(dvar, 1);                                                      \
        dvar += __shfl_xor(dvar, 2);                                                      \
        dvar += __shfl_xor(dvar, 4);                                                      \
    }

#define VADD(slot, p)                                                                     \
    {                                                                                     \
        const __half2* vh = reinterpret_cast<const __half2*>(&vr##slot);                  \
        float2 v01 = __half22float2(vh[0]), v23 = __half22float2(vh[1]);                  \
        acc.x = fmaf(p, v01.x, acc.x);                                                    \
        acc.y = fmaf(p, v01.y, acc.y);                                                    \
        acc.z = fmaf(p, v23.x, acc.z);                                                    \
        acc.w = fmaf(p, v23.y, acc.w);                                                    \
    }

    for (; idx + 3 < end; idx += 4) {
        int s0 = csr_src[idx], s1 = csr_src[idx + 1];
        int s2 = csr_src[idx + 2], s3 = csr_src[idx + 3];
        LOAD_KV(0, s0) LOAD_KV(1, s1) LOAD_KV(2, s2) LOAD_KV(3, s3)
        DOT(0, e0) DOT(1, e1) DOT(2, e2) DOT(3, e3)
        float mn = fmaxf(fmaxf(fmaxf(m, e0), fmaxf(e1, e2)), e3);
        float c  = __expf(m - mn);
        float p0 = __expf(e0 - mn), p1 = __expf(e1 - mn);
        float p2 = __expf(e2 - mn), p3 = __expf(e3 - mn);
        s = fmaf(s, c, (p0 + p1) + (p2 + p3));
        acc.x *= c; acc.y *= c; acc.z *= c; acc.w *= c;
        VADD(0, p0) VADD(1, p1) VADD(2, p2) VADD(3, p3)
        m = mn;
    }
    for (; idx < end; ++idx) {
        int s0 = csr_src[idx];
        LOAD_KV(0, s0)
        DOT(0, e0)
        float mn = fmaxf(m, e0);
        float c = __expf(m - mn);
        float p0 = __expf(e0 - mn);
        s = fmaf(s, c, p0);
        acc.x *= c; acc.y *= c; acc.z *= c; acc.w *= c;
        VADD(0, p0)
        m = mn;
    }
#undef LOAD_KV
#undef DOT
#undef VADD

    float inv = (s > 0.f) ? 1.f / s : 0.f;
    __half2 o01 = __floats2half2_rn(acc.x * inv, acc.y * inv);
    __half2 o23 = __floats2half2_rn(acc.z * inv, acc.w * inv);
    union { __half2 h2[2]; float2 f2; } u;
    u.h2[0] = o01; u.h2[1] = o23;
    *reinterpret_cast<float2*>(&h_out[(size_t)node * HID + loff]) = u.f2;
}

extern "C" void kernel_launch(void* const* d_in, const int* in_sizes, int n_in,
                              void* d_out, int out_size, void* d_ws, size_t ws_size,
                              hipStream_t stream) {
    const float* X    = (const float*)d_in[0];
    const int*   src  = (const int*)d_in[1];
    const int*   dst  = (const int*)d_in[2];
    const float* Win  = (const float*)d_in[3];
    const float* bin_ = (const float*)d_in[4];
    const float* Wq   = (const float*)d_in[5];
    const float* Wk   = (const float*)d_in[6];
    const float* Wv   = (const float*)d_in[7];
    const float* bq   = (const float*)d_in[8];
    const float* bk   = (const float*)d_in[9];
    const float* bv   = (const float*)d_in[10];
    const float* Wout = (const float*)d_in[11];
    const float* bout = (const float*)d_in[12];
    float* out = (float*)d_out;

    char* ws = (char*)d_ws;
    size_t off = 0;
    auto alloc = [&](size_t bytes) -> void* {
        void* p = ws + off;
        off = (off + bytes + 255) & ~(size_t)255;
        return p;
    };
    _Float16* qkv   = (_Float16*)alloc((size_t)MPAD * QKVW * 2);
    _Float16* h     = (_Float16*)alloc((size_t)MPAD * HID * 2);
    _Float16* Xf    = (_Float16*)alloc((size_t)MPAD * IN_DIM * 2);
    _Float16* Wqkvt = (_Float16*)alloc((size_t)N_LAYERS * QKVW * HID * 2);
    _Float16* Wint  = (_Float16*)alloc((size_t)HID * IN_DIM * 2);
    _Float16* Wot_h = (_Float16*)alloc((size_t)128 * HID * 2);
    _Float16* Wot_l = (_Float16*)alloc((size_t)128 * HID * 2);
    int* cnt     = (int*)alloc(sizeof(int) * 2 * N_NODES);   // [hist | scatter-cursor]
    int* row_off = (int*)alloc(sizeof(int) * (N_NODES + 1));
    int* csr_src = (int*)alloc(sizeof(int) * N_EDGES);

    // CSR build (one memset covers both counter arrays)
    hipMemsetAsync(cnt, 0, sizeof(int) * 2 * N_NODES, stream);
    hist_kernel<<<(N_EDGES + 255) / 256, 256, 0, stream>>>(dst, cnt, N_EDGES);
    scan_kernel<<<1, 1024, 0, stream>>>(cnt, row_off, N_NODES);
    scatter_kernel<<<(N_EDGES + 255) / 256, 256, 0, stream>>>(src, dst, row_off,
                                                              cnt + N_NODES, csr_src, N_EDGES);

    // conversions
    {
        int t1 = N_LAYERS * QKVW * HID;
        wqkv_cvt_kernel<<<(t1 + 255) / 256, 256, 0, stream>>>(Wq, Wk, Wv, Wqkvt);
        int t2 = HID * IN_DIM;
        win_cvt_kernel<<<(t2 + 255) / 256, 256, 0, stream>>>(Win, Wint);
        int t3 = 128 * HID;
        wout_cvt_kernel<<<(t3 + 255) / 256, 256, 0, stream>>>(Wout, Wot_h, Wot_l);
        int t4 = MPAD * IN_DIM;
        x_cvt_kernel<<<(t4 + 255) / 256, 256, 0, stream>>>(X, Xf);
    }

    dim3 blk(256);
    const int NQ = 8 * ((NRB + 7) / 8);   // 392 row-slots
    // in_proj: h = X @ Win + bin  (fp16 out, ldC=256), K=128 -> NT=4, 2 col-tiles
    gemm16<4, 2><<<dim3(NQ * 2), blk, 0, stream>>>(
        Xf, Wint, bin_, bin_, bin_, 1.f, h, HID);

    for (int l = 0; l < N_LAYERS; ++l) {
        const _Float16* Bl = Wqkvt + (size_t)l * QKVW * HID;
        // fused QKV: qkv[m][0:768] = (h@Wq+bq)*sc | h@Wk+bk | h@Wv+bv ; K=256 -> NT=8
        gemm16<8, 6><<<dim3(NQ * 6), blk, 0, stream>>>(
            h, Bl, bq + l * HID, bk + l * HID, bv + l * HID, SCALING, qkv, QKVW);
        attn_kernel<<<(N_NODES + 3) / 4, blk, 0, stream>>>(
            qkv, row_off, csr_src, h, N_NODES);
    }
    // out_proj
    gemm_out<<<dim3(NRB), blk, 0, stream>>>(
        h, Wot_h, Wot_l, bout, out, HID);
}